// Round 10
// baseline (259.137 us; speedup 1.0000x reference)
//
#include <hip/hip_runtime.h>
#include <math.h>

#define POOL 7
#define NPOS 49      // 7*7
#define CCH 256      // channels
#define NBKT 256     // sort buckets: lvl(2b) | batch(1b) | ybucket(5b)

// ---- shared level computation (must match reference exactly) ----
__device__ __forceinline__ int compute_level(const float* __restrict__ boxes,
                                             float cc, int box) {
    const float y1 = boxes[box * 4 + 0];
    const float x1 = boxes[box * 4 + 1];
    const float y2 = boxes[box * 4 + 2];
    const float x2 = boxes[box * 4 + 3];
    const float h = y2 - y1;
    const float w = x2 - x1;
    const float roi = log2f(sqrtf(h * w) / cc);
    int lvl = 4 + (int)rintf(roi);   // rintf = round half to even, matches jnp.round
    return min(max(lvl, 2), 5);
}

__device__ __forceinline__ int sort_key(const float* __restrict__ boxes,
                                        float cc, int box, int N, int* lvl_out) {
    const int lvl = compute_level(boxes, cc, box);
    *lvl_out = lvl;
    const int b = box / N;
    const float yc = 0.5f * (boxes[box * 4 + 0] + boxes[box * 4 + 2]);
    const int yb = min(31, max(0, (int)(yc * 32.0f)));
    return ((lvl - 2) << 6) | (b << 5) | yb;
}

// Kernel A: counting-sort 2000 boxes by (level, batch, y-band) into d_ws.
// Spatial key makes the co-resident window's gather footprint ~1-2MB -> fits
// the 4MB per-XCD L2 (level-only sort left it at the full 8.4MB f4 map).
__global__ __launch_bounds__(256) void level_sort_kernel(
    const float* __restrict__ boxes, const float* __restrict__ meta,
    int2* __restrict__ order, int nBoxes, int N)
{
    __shared__ int cnt[NBKT];
    __shared__ int base[NBKT];
    __shared__ int cur[NBKT];
    const float area = meta[4] * meta[5];
    const float cc = 224.0f / sqrtf(area);

    for (int i = threadIdx.x; i < NBKT; i += blockDim.x) { cnt[i] = 0; cur[i] = 0; }
    __syncthreads();
    for (int i = threadIdx.x; i < nBoxes; i += blockDim.x) {
        int lvl;
        atomicAdd(&cnt[sort_key(boxes, cc, i, N, &lvl)], 1);
    }
    __syncthreads();
    if (threadIdx.x == 0) {
        int s = 0;
        for (int k = 0; k < NBKT; ++k) { base[k] = s; s += cnt[k]; }
    }
    __syncthreads();
    for (int i = threadIdx.x; i < nBoxes; i += blockDim.x) {
        int lvl;
        const int k = sort_key(boxes, cc, i, N, &lvl);
        const int slot = base[k] + atomicAdd(&cur[k], 1);
        order[slot] = make_int2(i, lvl);
    }
}

// Kernel B: one wave (64 lanes) per (sorted-box, py, px) output position.
// Each lane: 4 channels as float4 -> 64 lanes x 16B = 1KB coalesced.
__global__ __launch_bounds__(256) void roialign_kernel(
    const float* __restrict__ boxes,   // [B*N, 4] (y1,x1,y2,x2)
    const int2* __restrict__ order,    // [B*N] {boxIdx, lvl} sorted
    const float* __restrict__ f2,      // [B,256,256,256]
    const float* __restrict__ f3,      // [B,128,128,256]
    const float* __restrict__ f4,      // [B, 64, 64,256]
    const float* __restrict__ f5,      // [B, 32, 32,256]
    float* __restrict__ out,           // [B*N, 7, 7, 256]
    int nPos, int N)
{
    const int wave = threadIdx.x >> 6;
    const int lane = threadIdx.x & 63;
    const int pos  = blockIdx.x * 4 + wave;
    if (pos >= nPos) return;

    const int sp  = pos / NPOS;            // sorted slot
    const int p   = pos - sp * NPOS;
    const int py  = p / POOL;
    const int px  = p - py * POOL;

    const int2 oi = order[sp];
    const int box = oi.x;
    const int lvl = oi.y;
    const int b   = box / N;

    const float y1 = boxes[box * 4 + 0];
    const float x1 = boxes[box * 4 + 1];
    const float y2 = boxes[box * 4 + 2];
    const float x2 = boxes[box * 4 + 3];
    const float h = y2 - y1;
    const float w = x2 - x1;

    const float* fm;
    int H;
    if      (lvl == 2) { fm = f2; H = 256; }
    else if (lvl == 3) { fm = f3; H = 128; }
    else if (lvl == 4) { fm = f4; H = 64;  }
    else               { fm = f5; H = 32;  }

    const float Hm1 = (float)(H - 1);
    // ys = y1*(H-1) + gy * ((y2-y1)*(H-1)/(ph-1))   (match reference op order)
    const float step_y = h * Hm1 / 6.0f;
    const float step_x = w * Hm1 / 6.0f;
    const float ysf = y1 * Hm1 + (float)py * step_y;
    const float xsf = x1 * Hm1 + (float)px * step_x;

    const float y0f = floorf(ysf);
    const float x0f = floorf(xsf);
    const float wy = ysf - y0f;            // unclipped fractional weights
    const float wx = xsf - x0f;

    const int y0i = min(max((int)y0f, 0), H - 1);
    const int y1i = min((int)y0f + 1, H - 1);
    const int x0i = min(max((int)x0f, 0), H - 1);
    const int x1i = min((int)x0f + 1, H - 1);

    // ---- gather 4 neighbors, 4 channels per lane ----
    const size_t rowT = ((size_t)b * H + (size_t)y0i) * (size_t)H;
    const size_t rowB = ((size_t)b * H + (size_t)y1i) * (size_t)H;
    const size_t c0   = (size_t)lane * 4;

    const float4 tl = *(const float4*)(fm + (rowT + x0i) * CCH + c0);
    const float4 tr = *(const float4*)(fm + (rowT + x1i) * CCH + c0);
    const float4 bl = *(const float4*)(fm + (rowB + x0i) * CCH + c0);
    const float4 br = *(const float4*)(fm + (rowB + x1i) * CCH + c0);

    // top = tl + (tr-tl)*wx; bot = bl + (br-bl)*wx; res = top + (bot-top)*wy
    float4 o;
    {
        float top, bot;
        top = tl.x + (tr.x - tl.x) * wx;  bot = bl.x + (br.x - bl.x) * wx;  o.x = top + (bot - top) * wy;
        top = tl.y + (tr.y - tl.y) * wx;  bot = bl.y + (br.y - bl.y) * wx;  o.y = top + (bot - top) * wy;
        top = tl.z + (tr.z - tl.z) * wx;  bot = bl.z + (br.z - bl.z) * wx;  o.z = top + (bot - top) * wy;
        top = tl.w + (tr.w - tl.w) * wx;  bot = bl.w + (br.w - bl.w) * wx;  o.w = top + (bot - top) * wy;
    }

    // Plain store (NT store reverted — suspected +7us regression in R7).
    *(float4*)(out + (size_t)box * NPOS * CCH + (size_t)p * CCH + c0) = o;
}

extern "C" void kernel_launch(void* const* d_in, const int* in_sizes, int n_in,
                              void* d_out, int out_size, void* d_ws, size_t ws_size,
                              hipStream_t stream) {
    const float* boxes = (const float*)d_in[0];
    const float* meta  = (const float*)d_in[1];
    const float* f2    = (const float*)d_in[2];
    const float* f3    = (const float*)d_in[3];
    const float* f4    = (const float*)d_in[4];
    const float* f5    = (const float*)d_in[5];
    float* out = (float*)d_out;
    int2* order = (int2*)d_ws;                 // 2000 * 8B = 16KB scratch

    const int nBoxes = in_sizes[0] / 4;        // B*N = 2000
    const int B      = in_sizes[1] / 93;       // 2
    const int N      = nBoxes / B;             // 1000
    const int nPos   = nBoxes * NPOS;          // 98000

    level_sort_kernel<<<1, 256, 0, stream>>>(boxes, meta, order, nBoxes, N);

    const int blocks = (nPos + 3) / 4;         // 4 waves (positions) per block
    roialign_kernel<<<blocks, 256, 0, stream>>>(boxes, order, f2, f3, f4, f5,
                                                out, nPos, N);
}

// Round 11
// 249.151 us; speedup vs baseline: 1.0401x; 1.0401x over previous
//
#include <hip/hip_runtime.h>
#include <math.h>

#define POOL 7
#define NPOS 49      // 7*7
#define CCH 256      // channels
#define NXCD 8
#define POS_PER_BLK 16   // 16 waves x 1 position

// One wave (64 lanes) per (box, py, px) output position; 16 positions/block.
// Each lane: 4 channels as float4 -> 64 lanes x 16B = 1KB coalesced.
// Chunked XCD swizzle: consecutive position ranges stay on one XCD's L2,
// so a box's feature rows are filled into exactly one L2 (was: up to 8).
__global__ __launch_bounds__(1024) void roialign_kernel(
    const float* __restrict__ boxes,   // [B*N, 4] (y1,x1,y2,x2)
    const float* __restrict__ meta,    // [B, 93]
    const float* __restrict__ f2,      // [B,256,256,256]
    const float* __restrict__ f3,      // [B,128,128,256]
    const float* __restrict__ f4,      // [B, 64, 64,256]
    const float* __restrict__ f5,      // [B, 32, 32,256]
    float* __restrict__ out,           // [B*N, 7, 7, 256]
    int nPos, int N, int nblk)
{
    // ---- bijective chunked XCD swizzle (m204): hw round-robins bid%8 ----
    const int bid = blockIdx.x;
    const int q = nblk / NXCD, r = nblk % NXCD;
    const int xcd = bid % NXCD, idx = bid / NXCD;
    const int wgid = (xcd < r ? xcd * (q + 1) : r * (q + 1) + (xcd - r) * q) + idx;

    const int wave = threadIdx.x >> 6;
    const int lane = threadIdx.x & 63;
    const int pos  = wgid * POS_PER_BLK + wave;
    if (pos >= nPos) return;

    const int box = pos / NPOS;
    const int p   = pos - box * NPOS;
    const int py  = p / POOL;
    const int px  = p - py * POOL;
    const int b   = box / N;

    // ---- per-box scalars (wave-uniform; redundant across lanes, cheap) ----
    const float y1 = boxes[box * 4 + 0];
    const float x1 = boxes[box * 4 + 1];
    const float y2 = boxes[box * 4 + 2];
    const float x2 = boxes[box * 4 + 3];
    const float h = y2 - y1;
    const float w = x2 - x1;

    // roi_level = clip(4 + round(log2(sqrt(h*w) / (224/sqrt(area)))), 2, 5)
    const float area = meta[4] * meta[5];
    const float cc   = 224.0f / sqrtf(area);
    const float roi  = log2f(sqrtf(h * w) / cc);
    int lvl = 4 + (int)rintf(roi);     // rintf = round half to even, matches jnp.round
    lvl = min(max(lvl, 2), 5);

    const float* fm;
    int H;
    if      (lvl == 2) { fm = f2; H = 256; }
    else if (lvl == 3) { fm = f3; H = 128; }
    else if (lvl == 4) { fm = f4; H = 64;  }
    else               { fm = f5; H = 32;  }

    const float Hm1 = (float)(H - 1);
    // ys = y1*(H-1) + gy * ((y2-y1)*(H-1)/(ph-1))   (match reference op order)
    const float step_y = h * Hm1 / 6.0f;
    const float step_x = w * Hm1 / 6.0f;
    const float ysf = y1 * Hm1 + (float)py * step_y;
    const float xsf = x1 * Hm1 + (float)px * step_x;

    const float y0f = floorf(ysf);
    const float x0f = floorf(xsf);
    const float wy = ysf - y0f;            // unclipped fractional weights
    const float wx = xsf - x0f;

    const int y0i = min(max((int)y0f, 0), H - 1);
    const int y1i = min((int)y0f + 1, H - 1);
    const int x0i = min(max((int)x0f, 0), H - 1);
    const int x1i = min((int)x0f + 1, H - 1);

    // ---- gather 4 neighbors, 4 channels per lane ----
    const size_t rowT = ((size_t)b * H + (size_t)y0i) * (size_t)H;
    const size_t rowB = ((size_t)b * H + (size_t)y1i) * (size_t)H;
    const size_t c0   = (size_t)lane * 4;

    const float4 tl = *(const float4*)(fm + (rowT + x0i) * CCH + c0);
    const float4 tr = *(const float4*)(fm + (rowT + x1i) * CCH + c0);
    const float4 bl = *(const float4*)(fm + (rowB + x0i) * CCH + c0);
    const float4 br = *(const float4*)(fm + (rowB + x1i) * CCH + c0);

    // top = tl + (tr-tl)*wx; bot = bl + (br-bl)*wx; res = top + (bot-top)*wy
    float4 o;
    {
        float top, bot;
        top = tl.x + (tr.x - tl.x) * wx;  bot = bl.x + (br.x - bl.x) * wx;  o.x = top + (bot - top) * wy;
        top = tl.y + (tr.y - tl.y) * wx;  bot = bl.y + (br.y - bl.y) * wx;  o.y = top + (bot - top) * wy;
        top = tl.z + (tr.z - tl.z) * wx;  bot = bl.z + (br.z - bl.z) * wx;  o.z = top + (bot - top) * wy;
        top = tl.w + (tr.w - tl.w) * wx;  bot = bl.w + (br.w - bl.w) * wx;  o.w = top + (bot - top) * wy;
    }

    *(float4*)(out + (size_t)pos * CCH + c0) = o;
}

extern "C" void kernel_launch(void* const* d_in, const int* in_sizes, int n_in,
                              void* d_out, int out_size, void* d_ws, size_t ws_size,
                              hipStream_t stream) {
    const float* boxes = (const float*)d_in[0];
    const float* meta  = (const float*)d_in[1];
    const float* f2    = (const float*)d_in[2];
    const float* f3    = (const float*)d_in[3];
    const float* f4    = (const float*)d_in[4];
    const float* f5    = (const float*)d_in[5];
    float* out = (float*)d_out;

    const int nBoxes = in_sizes[0] / 4;        // B*N = 2000
    const int B      = in_sizes[1] / 93;       // 2
    const int N      = nBoxes / B;             // 1000
    const int nPos   = nBoxes * NPOS;          // 98000

    const int nblk = (nPos + POS_PER_BLK - 1) / POS_PER_BLK;   // 6125
    roialign_kernel<<<nblk, 1024, 0, stream>>>(boxes, meta, f2, f3, f4, f5,
                                               out, nPos, N, nblk);
}